// Round 1
// 1000.017 us; speedup vs baseline: 24.0793x; 24.0793x over previous
//
#include <hip/hip_runtime.h>
#include <stdint.h>

// ---------------------------------------------------------------------------
// AVAttention — ROUND 6: replace naive VALU GEMMs (MfmaUtil=0) with MFMA
// 128x128-tile bf16 GEMM (m97 structure: 4 waves, 16x16x32_bf16, BK=32,
// global_load_lds width-16 staging, 2 barriers/K-step).
// Prep phase converts everything to bf16 A[M][K] / Bt[N][K] row-major:
//   g [B,2560,T] -> gT [B,T,2560] bf16  (LDS tiled transpose)  -> in d_out
//   weights [K][N] -> [N][K] bf16; biases -> fp32               -> in ws
// d_out (167.77MB) arena timeline:
//   phase 1: gT (167.77MB, exact fit)  [dead after q-proj]
//   phase 2: ph_bf@0 (16MB) | k@16MB | vT@32MB | sc@48MB (67MB)
//   phase 3: final GEMM overwrites all of d_out with fp32 out.
// ws usage ~39MB (under previously-proven 48MB): weightsT+biases+q/val buf.
// ---------------------------------------------------------------------------

typedef __attribute__((ext_vector_type(4))) float f32x4;
typedef __attribute__((ext_vector_type(8))) short bf16x8;

#define AS1 __attribute__((address_space(1)))
#define AS3 __attribute__((address_space(3)))

__device__ __forceinline__ ushort f2b(float x) {
    union { float f; uint32_t u; } v; v.f = x;
    uint32_t r = (v.u + 0x7FFFu + ((v.u >> 16) & 1u)) >> 16;
    return (ushort)r;
}
__device__ __forceinline__ float b2f(ushort u) {
    union { uint32_t u; float f; } v; v.u = ((uint32_t)u) << 16;
    return v.f;
}

__device__ __forceinline__ void gload16(const void* g, void* l) {
    __builtin_amdgcn_global_load_lds((const AS1 uint32_t*)g,
                                     (AS3 uint32_t*)l, 16, 0, 0);
}

// flag: 1 = inputs bf16, 0 = fp32 (low half of fp32 word is random mantissa).
__global__ void sniff_dtype(const uint32_t* __restrict__ ph, int* __restrict__ flag)
{
    if (threadIdx.x == 0 && blockIdx.x == 0) {
        int cnt = 0;
        for (int i = 0; i < 64; ++i) {
            uint32_t e = (ph[i] >> 7) & 0xFFu;
            if (e >= 90u && e <= 140u) ++cnt;
        }
        *flag = (cnt >= 40) ? 1 : 0;
    }
}

// ---------------- prep kernels (memory-bound, cheap) -----------------------

// bias -> fp32
__global__ __launch_bounds__(256)
void cvt_bias(const void* __restrict__ src, float* __restrict__ dst, int n,
              const int* __restrict__ flag)
{
    int i = blockIdx.x * 256 + threadIdx.x;
    if (i >= n) return;
    dst[i] = (*flag == 0) ? ((const float*)src)[i]
                          : b2f(((const ushort*)src)[i]);
}

// contiguous convert to bf16, 8 elems/thread
__global__ __launch_bounds__(256)
void cvt_bf16(const void* __restrict__ src, ushort* __restrict__ dst, int n8,
              const int* __restrict__ flag)
{
    int i = blockIdx.x * 256 + threadIdx.x;
    if (i >= n8) return;
    if (*flag == 0) {
        const float4* s = (const float4*)src;
        float4 a = s[2 * i], b = s[2 * i + 1];
        uint4 o;
        o.x = (uint32_t)f2b(a.x) | ((uint32_t)f2b(a.y) << 16);
        o.y = (uint32_t)f2b(a.z) | ((uint32_t)f2b(a.w) << 16);
        o.z = (uint32_t)f2b(b.x) | ((uint32_t)f2b(b.y) << 16);
        o.w = (uint32_t)f2b(b.z) | ((uint32_t)f2b(b.w) << 16);
        ((uint4*)dst)[i] = o;
    } else {
        ((uint4*)dst)[i] = ((const uint4*)src)[i];
    }
}

// src [z][R][Cc] (fp32/bf16) -> dst [z][Cc][R] bf16. 32x32 LDS tile.
__global__ __launch_bounds__(256)
void transpose_cvt(const void* __restrict__ src, ushort* __restrict__ dst,
                   int R, int Cc, long sbat, long dbat,
                   const int* __restrict__ flag)
{
    __shared__ ushort tile[32][33];
    const bool isf32 = (*flag == 0);
    const int r0 = blockIdx.y * 32, c0 = blockIdx.x * 32;
    const int tr = threadIdx.x >> 3;         // 0..31
    const int tc4 = (threadIdx.x & 7) * 4;   // 0,4,..,28

    const char* sb = (const char*)src + (size_t)blockIdx.z * sbat * (isf32 ? 4 : 2);
    if (isf32) {
        const float4* s = (const float4*)((const float*)sb + (size_t)(r0 + tr) * Cc + c0 + tc4);
        float4 v = *s;
        tile[tr][tc4 + 0] = f2b(v.x); tile[tr][tc4 + 1] = f2b(v.y);
        tile[tr][tc4 + 2] = f2b(v.z); tile[tr][tc4 + 3] = f2b(v.w);
    } else {
        const ushort4* s = (const ushort4*)((const ushort*)sb + (size_t)(r0 + tr) * Cc + c0 + tc4);
        ushort4 v = *s;
        tile[tr][tc4 + 0] = v.x; tile[tr][tc4 + 1] = v.y;
        tile[tr][tc4 + 2] = v.z; tile[tr][tc4 + 3] = v.w;
    }
    __syncthreads();
    ushort4 o;
    o.x = tile[tc4 + 0][tr]; o.y = tile[tc4 + 1][tr];
    o.z = tile[tc4 + 2][tr]; o.w = tile[tc4 + 3][tr];
    *(ushort4*)(dst + (size_t)blockIdx.z * dbat + (size_t)(c0 + tr) * R + r0 + tc4) = o;
}

// ---------------- MFMA GEMM (m97 structure) --------------------------------
// C[M,N] = scale * (A[M,K] @ Bt[N,K]^T) + bias[n]
// A,Bt bf16 row-major (lda=ldb=K). 256 thr = 4 waves 2x2; 128x128 tile; BK=32.
// STORE 0: bf16 C[m*ldc+n];  1: bf16 transposed C[n*ldc+m] (8B stores);
// STORE 2: fp32 final out[(n&63)*40960 + (n>>6)*2048 + m] (float4 stores).
template<int STORE>
__global__ __launch_bounds__(256)
void mfma_gemm(const ushort* __restrict__ A, const ushort* __restrict__ Bt,
               void* __restrict__ C, const float* __restrict__ bias,
               int M, int N, int K,
               long Abat, long Bbat, long Cbat, long ldc, float scale)
{
    __shared__ ushort As[128 * 32];   // [row][k] linear (global_load_lds dest)
    __shared__ ushort Bs[128 * 32];

    const int tid = threadIdx.x;
    const int lane = tid & 63;
    const int wave = tid >> 6;
    const int wr = wave >> 1, wc = wave & 1;
    const int m0 = blockIdx.y * 128, n0 = blockIdx.x * 128;

    const ushort* Ab = A + (size_t)blockIdx.z * Abat;
    const ushort* Bb = Bt + (size_t)blockIdx.z * Bbat;

    // staging: thread tid covers row=tid>>2 (then +64), 8 elems at k=(tid&3)*8
    const int srow = tid >> 2;
    const int scol = (tid & 3) * 8;
    const ushort* gA = Ab + (size_t)(m0 + srow) * K + scol;
    const ushort* gB = Bb + (size_t)(n0 + srow) * K + scol;
    const size_t rowskip = (size_t)64 * K;
    ushort* lA = As + tid * 8;   // byte tid*16: wave-uniform base + lane*16
    ushort* lB = Bs + tid * 8;

    // fragment read addrs: lane holds A[fr][fk..fk+7]
    const int fr = lane & 15;
    const int fk = (lane >> 4) * 8;
    const ushort* pa = As + (size_t)(wr * 64 + fr) * 32 + fk;
    const ushort* pb = Bs + (size_t)(wc * 64 + fr) * 32 + fk;

    f32x4 acc[4][4] = {};

    for (int k0 = 0; k0 < K; k0 += 32) {
        gload16(gA, lA);
        gload16(gA + rowskip, lA + 2048);
        gload16(gB, lB);
        gload16(gB + rowskip, lB + 2048);
        gA += 32; gB += 32;
        __syncthreads();          // drains vmcnt(0) before reads

        bf16x8 af[4], bf[4];
#pragma unroll
        for (int i = 0; i < 4; ++i) af[i] = *(const bf16x8*)(pa + (size_t)i * 16 * 32);
#pragma unroll
        for (int i = 0; i < 4; ++i) bf[i] = *(const bf16x8*)(pb + (size_t)i * 16 * 32);
#pragma unroll
        for (int mi = 0; mi < 4; ++mi)
#pragma unroll
            for (int ni = 0; ni < 4; ++ni)
                acc[mi][ni] = __builtin_amdgcn_mfma_f32_16x16x32_bf16(
                    af[mi], bf[ni], acc[mi][ni], 0, 0, 0);
        __syncthreads();          // protect LDS from next-iter staging
    }

    // epilogue: C/D layout col=lane&15, row=(lane>>4)*4+reg  [verified m89]
    const int nb = n0 + wc * 64;
    const int mb = m0 + wr * 64 + (lane >> 4) * 4;
#pragma unroll
    for (int ni = 0; ni < 4; ++ni) {
        const int n = nb + ni * 16 + fr;
        const float bv = bias ? bias[n] : 0.f;
#pragma unroll
        for (int mi = 0; mi < 4; ++mi) {
            f32x4 v = acc[mi][ni];
            const int m = mb + mi * 16;
            if (STORE == 0) {
                ushort* Cc = (ushort*)C + (size_t)blockIdx.z * Cbat;
#pragma unroll
                for (int r = 0; r < 4; ++r)
                    Cc[(size_t)(m + r) * ldc + n] = f2b(v[r] * scale + bv);
            } else if (STORE == 1) {
                ushort* Cc = (ushort*)C + (size_t)blockIdx.z * Cbat;
                ushort4 o;
                o.x = f2b(v[0] * scale + bv); o.y = f2b(v[1] * scale + bv);
                o.z = f2b(v[2] * scale + bv); o.w = f2b(v[3] * scale + bv);
                *(ushort4*)(Cc + (size_t)n * ldc + m) = o;
            } else {
                float* Cf = (float*)C + (size_t)blockIdx.z * Cbat;
                float4 o = { v[0] * scale + bv, v[1] * scale + bv,
                             v[2] * scale + bv, v[3] * scale + bv };
                *(float4*)(Cf + (size_t)(n & 63) * (20 * 2048)
                              + (size_t)(n >> 6) * 2048 + m) = o;
            }
        }
    }
}

// ---------------- masked softmax (unchanged, proven) -----------------------
__global__ __launch_bounds__(256)
void softmax_mask(ushort* __restrict__ sc, const int* __restrict__ lengths)
{
    const int t = blockIdx.x, b = blockIdx.y, tid = threadIdx.x;
    const bool is64 = (lengths[1] == 0 && lengths[3] == 0 && lengths[5] == 0);
    const int len = is64 ? lengths[2 * b] : lengths[b];

    ushort* row = sc + ((size_t)b * 2048 + t) * 1024;
    const int s0 = tid * 4;
    uint2 pk = *(const uint2*)(row + s0);
    ushort u[4] = { (ushort)(pk.x & 0xffff), (ushort)(pk.x >> 16),
                    (ushort)(pk.y & 0xffff), (ushort)(pk.y >> 16) };
    float v[4];
    float mx = -INFINITY;
#pragma unroll
    for (int j = 0; j < 4; ++j) {
        v[j] = (s0 + j < len) ? b2f(u[j]) : -INFINITY;
        mx = fmaxf(mx, v[j]);
    }
    for (int off = 32; off > 0; off >>= 1) mx = fmaxf(mx, __shfl_xor(mx, off));
    __shared__ float redm[4], reds[4];
    const int w = tid >> 6;
    if ((tid & 63) == 0) redm[w] = mx;
    __syncthreads();
    mx = fmaxf(fmaxf(redm[0], redm[1]), fmaxf(redm[2], redm[3]));

    float e[4]; float sum = 0.f;
#pragma unroll
    for (int j = 0; j < 4; ++j) { e[j] = __expf(v[j] - mx); sum += e[j]; }
    for (int off = 32; off > 0; off >>= 1) sum += __shfl_xor(sum, off);
    if ((tid & 63) == 0) reds[w] = sum;
    __syncthreads();
    sum = reds[0] + reds[1] + reds[2] + reds[3];
    const float inv = 1.0f / sum;

    ushort o[4];
#pragma unroll
    for (int j = 0; j < 4; ++j) o[j] = f2b(e[j] * inv);
    uint2 opk;
    opk.x = (uint32_t)o[0] | ((uint32_t)o[1] << 16);
    opk.y = (uint32_t)o[2] | ((uint32_t)o[3] << 16);
    *(uint2*)(row + s0) = opk;
}

// ---------------------------------------------------------------------------
extern "C" void kernel_launch(void* const* d_in, const int* in_sizes, int n_in,
                              void* d_out, int out_size, void* d_ws, size_t ws_size,
                              hipStream_t stream)
{
    const void* ph   = d_in[0];   // [16,1024,512]
    const void* g    = d_in[1];   // [16,2560,2048]
    const int*  len  = (const int*)d_in[2];
    const void* Wk   = d_in[3];   // [512,512]  W[k][n]
    const void* bk   = d_in[4];
    const void* Wv   = d_in[5];
    const void* bv   = d_in[6];
    const void* Wq   = d_in[7];   // [2560,512]
    const void* bq   = d_in[8];
    const void* Wmel = d_in[9];   // [512,1280]
    const void* bmel = d_in[10];
    void* out = d_out;            // [16,64,20,2048] fp32 = 167.77MB

    // ---- workspace (~39MB, under proven 48MB budget) ----
    char* ws = (char*)d_ws;
    size_t off = 0;
    auto alloc = [&](size_t bytes) -> char* {
        char* p = ws + off;
        off += (bytes + 255) & ~(size_t)255;
        return p;
    };
    int*    flag  = (int*)alloc(256);
    float*  bkf   = (float*)alloc(512 * 4);
    float*  bvf   = (float*)alloc(512 * 4);
    float*  bqf   = (float*)alloc(512 * 4);
    float*  bmelf = (float*)alloc(1280 * 4);
    ushort* WkT   = (ushort*)alloc((size_t)512 * 512 * 2);
    ushort* WvT   = (ushort*)alloc((size_t)512 * 512 * 2);
    ushort* WqT   = (ushort*)alloc((size_t)512 * 2560 * 2);
    ushort* WmelT = (ushort*)alloc((size_t)1280 * 512 * 2);
    ushort* qval  = (ushort*)alloc((size_t)16 * 2048 * 512 * 2);  // q, then val

    // ---- d_out arena ----
    char* dob = (char*)d_out;
    ushort* gT  = (ushort*)dob;                          // [16][2048][2560] phase 1
    ushort* phb = (ushort*)dob;                          // [16][1024][512]  phase 2
    ushort* kbf = (ushort*)(dob + 16777216);             // [16][1024][512]
    ushort* vT  = (ushort*)(dob + 33554432);             // [16][512][1024]
    ushort* sc  = (ushort*)(dob + 50331648);             // [16][2048][1024]

    sniff_dtype<<<1, 64, 0, stream>>>((const uint32_t*)ph, flag);

    // prep: transposes + conversions
    transpose_cvt<<<dim3(64, 80, 16), 256, 0, stream>>>(
        g, gT, 2560, 2048, 2560L * 2048, 2560L * 2048, flag);
    transpose_cvt<<<dim3(16, 16, 1), 256, 0, stream>>>(Wk, WkT, 512, 512, 0, 0, flag);
    transpose_cvt<<<dim3(16, 16, 1), 256, 0, stream>>>(Wv, WvT, 512, 512, 0, 0, flag);
    transpose_cvt<<<dim3(16, 80, 1), 256, 0, stream>>>(Wq, WqT, 2560, 512, 0, 0, flag);
    transpose_cvt<<<dim3(40, 16, 1), 256, 0, stream>>>(Wmel, WmelT, 512, 1280, 0, 0, flag);
    cvt_bias<<<2, 256, 0, stream>>>(bk, bkf, 512, flag);
    cvt_bias<<<2, 256, 0, stream>>>(bv, bvf, 512, flag);
    cvt_bias<<<2, 256, 0, stream>>>(bq, bqf, 512, flag);
    cvt_bias<<<5, 256, 0, stream>>>(bmel, bmelf, 1280, flag);

    // q[b][t][d] = gT[b] @ WqT^T + bq   (M=2048,N=512,K=2560) — gT dies here
    mfma_gemm<0><<<dim3(4, 16, 16), 256, 0, stream>>>(
        gT, WqT, qval, bqf, 2048, 512, 2560,
        2048L * 2560, 0, 2048L * 512, 512, 1.f);

    // ph -> bf16 into d_out@0 (gT dead)
    cvt_bf16<<<4096, 256, 0, stream>>>(ph, phb, 1048576, flag);

    // k[b][s][d] = ph_bf @ WkT^T + bk   (M=1024,N=512,K=512)
    mfma_gemm<0><<<dim3(4, 8, 16), 256, 0, stream>>>(
        phb, WkT, kbf, bkf, 1024, 512, 512,
        1024L * 512, 0, 1024L * 512, 512, 1.f);
    // vT[b][d][s] = (ph_bf @ WvT^T + bv)^T  (transposed store, ldc=S=1024)
    mfma_gemm<1><<<dim3(4, 8, 16), 256, 0, stream>>>(
        phb, WvT, vT, bvf, 1024, 512, 512,
        1024L * 512, 0, 512L * 1024, 1024, 1.f);

    // sc[b][t][s] = q @ k^T / sqrt(512)   (M=2048,N=1024,K=512)
    mfma_gemm<0><<<dim3(8, 16, 16), 256, 0, stream>>>(
        qval, kbf, sc, nullptr, 2048, 1024, 512,
        2048L * 512, 1024L * 512, 2048L * 1024, 1024, 0.044194173824159216f);

    softmax_mask<<<dim3(2048, 16), 256, 0, stream>>>(sc, len);

    // val[b][t][d] = P @ vT^T   (M=2048,N=512,K=1024) — overwrites dead q
    mfma_gemm<0><<<dim3(4, 16, 16), 256, 0, stream>>>(
        sc, vT, qval, nullptr, 2048, 512, 1024,
        2048L * 1024, 512L * 1024, 2048L * 512, 512, 1.f);

    // out[b][n&63][n>>6][t] = val @ WmelT^T + bmel  (fp32 final, overwrites d_out)
    mfma_gemm<2><<<dim3(10, 16, 16), 256, 0, stream>>>(
        qval, WmelT, out, bmelf, 2048, 1280, 512,
        2048L * 512, 0, 64L * 20 * 2048, 0, 1.f);
}